// Round 1
// baseline (165.348 us; speedup 1.0000x reference)
//
#include <hip/hip_runtime.h>
#include <hip/hip_bf16.h>
#include <hip/hip_fp16.h>

typedef _Float16 f16;
typedef _Float16 f16x8 __attribute__((ext_vector_type(8)));
typedef float f32x4 __attribute__((ext_vector_type(4)));

#define NB 4
#define SS 2048
#define DD 1024
#define OO 512

// ---------------- convert X f32 -> f16 (vectorized, 8 elems/thread) -------
__global__ __launch_bounds__(256) void cvt_x(const float* __restrict__ x,
                                             f16* __restrict__ y, int n8) {
  int i = blockIdx.x * 256 + threadIdx.x;
  if (i >= n8) return;
  const float4* xp = (const float4*)x + (size_t)i * 2;
  float4 a = xp[0], b = xp[1];
  f16x8 v;
  v[0] = (f16)a.x; v[1] = (f16)a.y; v[2] = (f16)a.z; v[3] = (f16)a.w;
  v[4] = (f16)b.x; v[5] = (f16)b.y; v[6] = (f16)b.z; v[7] = (f16)b.w;
  *((f16x8*)y + i) = v;
}

// ------------- transpose-convert W [D][O] f32 -> Wt [O][D] f16 ------------
__global__ __launch_bounds__(256) void cvt_wt(const float* __restrict__ w0,
                                              const float* __restrict__ w1,
                                              const float* __restrict__ w2,
                                              f16* __restrict__ wt) {
  const float* w = blockIdx.z == 0 ? w0 : (blockIdx.z == 1 ? w1 : w2);
  f16* out = wt + (size_t)blockIdx.z * OO * DD;
  __shared__ float t[64][65];
  int d0 = blockIdx.x * 64;  // grid.x = DD/64 = 16
  int o0 = blockIdx.y * 64;  // grid.y = OO/64 = 8
  int tid = threadIdx.x;
#pragma unroll
  for (int i = 0; i < 16; ++i) {
    int idx = i * 256 + tid;
    int r = idx >> 6, c = idx & 63;
    t[r][c] = w[(size_t)(d0 + r) * OO + (o0 + c)];
  }
  __syncthreads();
#pragma unroll
  for (int i = 0; i < 16; ++i) {
    int idx = i * 256 + tid;
    int r = idx >> 6, c = idx & 63;
    out[(size_t)(o0 + r) * DD + (d0 + c)] = (f16)t[c][r];
  }
}

// --------------- async global -> LDS, 16B per lane ------------------------
__device__ __forceinline__ void gload_lds16(const f16* g, f16* l) {
  __builtin_amdgcn_global_load_lds(
      (const __attribute__((address_space(1))) void*)g,
      (__attribute__((address_space(3))) void*)l, 16, 0, 0);
}

// --------------- GEMM, B-transposed form: C[m][n] = sum_k A[m][k]*B[n][k] --
// 128x128 tile, BK=64, 256 threads (4 waves, each wave a 64x64 subtile).
template <typename OUT_T>
__global__ __launch_bounds__(256) void gemm_bt(
    const f16* __restrict__ A, const f16* __restrict__ B, OUT_T* __restrict__ C,
    int M, int N, int K, int lda, int ldb, int ldc,
    long sAz, long sBz, long sCz, float scale) {
  A += (long)blockIdx.z * sAz;
  B += (long)blockIdx.z * sBz;
  C += (long)blockIdx.z * sCz;
  int tn = N >> 7;
  int bm = (int)blockIdx.x / tn, bn = (int)blockIdx.x % tn;

  __shared__ f16 As[128 * 64];
  __shared__ f16 Bs[128 * 64];

  int tid = threadIdx.x;
  int lane = tid & 63, wid = tid >> 6;
  int wr = (wid >> 1) << 6, wc = (wid & 1) << 6;

  f32x4 acc[4][4] = {};

  const f16* Ag = A + (long)(bm * 128) * lda;
  const f16* Bg = B + (long)(bn * 128) * ldb;

  int r = lane & 15, g = lane >> 4;

  for (int k0 = 0; k0 < K; k0 += 64) {
#pragma unroll
    for (int i = 0; i < 4; ++i) {
      int t = i * 256 + tid;
      int row = t >> 3;
      int col = (t & 7) << 3;
      gload_lds16(Ag + (long)row * lda + k0 + col, As + (i * 256 + (wid << 6)) * 8);
      gload_lds16(Bg + (long)row * ldb + k0 + col, Bs + (i * 256 + (wid << 6)) * 8);
    }
    __syncthreads();
#pragma unroll
    for (int kk = 0; kk < 64; kk += 32) {
      f16x8 af[4], bf[4];
#pragma unroll
      for (int m = 0; m < 4; ++m)
        af[m] = *(const f16x8*)&As[(wr + m * 16 + r) * 64 + kk + g * 8];
#pragma unroll
      for (int n = 0; n < 4; ++n)
        bf[n] = *(const f16x8*)&Bs[(wc + n * 16 + r) * 64 + kk + g * 8];
#pragma unroll
      for (int m = 0; m < 4; ++m)
#pragma unroll
        for (int n = 0; n < 4; ++n)
          acc[m][n] = __builtin_amdgcn_mfma_f32_16x16x32_f16(af[m], bf[n],
                                                             acc[m][n], 0, 0, 0);
    }
    __syncthreads();
  }

#pragma unroll
  for (int m = 0; m < 4; ++m)
#pragma unroll
    for (int n = 0; n < 4; ++n)
#pragma unroll
      for (int j = 0; j < 4; ++j) {
        int row = bm * 128 + wr + m * 16 + g * 4 + j;
        int col = bn * 128 + wc + n * 16 + r;
        C[(long)row * ldc + col] = (OUT_T)(acc[m][n][j] * scale);
      }
}

// --------------- row softmax, f32 in, f16 out (in-place alias) ------------
__global__ __launch_bounds__(256) void softmax_rows(float* __restrict__ Sc) {
  long row = blockIdx.x;  // 8192 rows
  float* s = Sc + row * SS;
  f16* p = (f16*)s;  // alias first half of the row
  int tid = threadIdx.x;
  int lane = tid & 63, wid = tid >> 6;
  float4 a = ((const float4*)s)[tid * 2];
  float4 b = ((const float4*)s)[tid * 2 + 1];
  float v[8] = {a.x, a.y, a.z, a.w, b.x, b.y, b.z, b.w};
  float mx = v[0];
#pragma unroll
  for (int j = 1; j < 8; ++j) mx = fmaxf(mx, v[j]);
#pragma unroll
  for (int off = 32; off; off >>= 1) mx = fmaxf(mx, __shfl_xor(mx, off));
  __shared__ float red[8];
  if (lane == 0) red[wid] = mx;
  __syncthreads();
  mx = fmaxf(fmaxf(red[0], red[1]), fmaxf(red[2], red[3]));
  float sum = 0.f;
#pragma unroll
  for (int j = 0; j < 8; ++j) {
    v[j] = __expf(v[j] - mx);
    sum += v[j];
  }
#pragma unroll
  for (int off = 32; off; off >>= 1) sum += __shfl_xor(sum, off);
  if (lane == 0) red[4 + wid] = sum;
  __syncthreads();
  float inv = 1.f / (red[4] + red[5] + red[6] + red[7]);
  f16x8 o;
#pragma unroll
  for (int j = 0; j < 8; ++j) o[j] = (f16)(v[j] * inv);
  *((f16x8*)p + tid) = o;
}

// ---------------------------------------------------------------------------
extern "C" void kernel_launch(void* const* d_in, const int* in_sizes, int n_in,
                              void* d_out, int out_size, void* d_ws,
                              size_t ws_size, hipStream_t stream) {
  const float* X = (const float*)d_in[0];
  const float* WQ = (const float*)d_in[1];
  const float* WK = (const float*)d_in[2];
  const float* WV = (const float*)d_in[3];
  float* out = (float*)d_out;

  char* ws = (char*)d_ws;
  f16* Xh = (f16*)ws;                          // 8192x1024 f16 = 16 MB
  f16* Wt = (f16*)(ws + 16777216);             // 3 x [512][1024] f16 = 3 MB
  f16* Qh = (f16*)(ws + 19922944);             // 8192x512 f16 = 8 MB
  f16* Kh = (f16*)(ws + 28311552);             // 8 MB
  f16* Vt = (f16*)(ws + 36700160);             // 4 x [512][2048] f16 = 8 MB
  float* Sc = (float*)(ws + 45088768);         // 4 x 2048x2048 f32 = 64 MB

  // 1) convert X
  cvt_x<<<4096, 256, 0, stream>>>(X, Xh, 1048576);
  // 2) transpose-convert weights
  cvt_wt<<<dim3(16, 8, 3), 256, 0, stream>>>(WQ, WK, WV, Wt);
  // 3) Q,K projections: [8192,1024] @ Wt^T -> [8192,512], z in {Q,K}
  gemm_bt<f16><<<dim3(256, 1, 2), 256, 0, stream>>>(
      Xh, Wt, Qh, 8192, 512, 1024, 1024, 1024, 512,
      0L, (long)OO * DD, (long)8192 * OO, 1.f);
  // 4) V^T projection per batch: [512,1024]=WtV @ Xb^T -> Vt[b][512][2048]
  gemm_bt<f16><<<dim3(64, 1, 4), 256, 0, stream>>>(
      Wt + 2 * OO * DD, Xh, Vt, 512, 2048, 1024, 1024, 1024, 2048,
      0L, (long)SS * DD, (long)OO * SS, 1.f);
  // 5) scores per batch: Q @ K^T / sqrt(512) -> f32
  gemm_bt<float><<<dim3(256, 1, 4), 256, 0, stream>>>(
      Qh, Kh, Sc, 2048, 2048, 512, 512, 512, 2048,
      (long)SS * OO, (long)SS * OO, (long)SS * SS, 0.04419417382415922f);
  // 6) softmax rows (writes f16 P in place over scores)
  softmax_rows<<<8192, 256, 0, stream>>>(Sc);
  // 7) out = P @ V : A=P (lda=4096 f16 elems, aliased), B=Vt -> f32 out
  gemm_bt<float><<<dim3(64, 1, 4), 256, 0, stream>>>(
      (const f16*)Sc, Vt, out, 2048, 512, 2048, 4096, 2048, 512,
      (long)SS * 4096, (long)OO * SS, (long)SS * OO, 1.f);
}

// Round 2
// 145.566 us; speedup vs baseline: 1.1359x; 1.1359x over previous
//
#include <hip/hip_runtime.h>
#include <hip/hip_bf16.h>
#include <hip/hip_fp16.h>

typedef _Float16 f16;
typedef _Float16 f16x8 __attribute__((ext_vector_type(8)));
typedef float f32x4 __attribute__((ext_vector_type(4)));

#define NB 4
#define SS 2048
#define DD 1024
#define OO 512

// ---------------- convert X f32 -> f16 (vectorized, 8 elems/thread) -------
__global__ __launch_bounds__(256) void cvt_x(const float* __restrict__ x,
                                             f16* __restrict__ y, int n8) {
  int i = blockIdx.x * 256 + threadIdx.x;
  if (i >= n8) return;
  const float4* xp = (const float4*)x + (size_t)i * 2;
  float4 a = xp[0], b = xp[1];
  f16x8 v;
  v[0] = (f16)a.x; v[1] = (f16)a.y; v[2] = (f16)a.z; v[3] = (f16)a.w;
  v[4] = (f16)b.x; v[5] = (f16)b.y; v[6] = (f16)b.z; v[7] = (f16)b.w;
  *((f16x8*)y + i) = v;
}

// ------------- transpose-convert W [D][O] f32 -> Wt [O][D] f16 ------------
__global__ __launch_bounds__(256) void cvt_wt(const float* __restrict__ w0,
                                              const float* __restrict__ w1,
                                              const float* __restrict__ w2,
                                              f16* __restrict__ wt) {
  const float* w = blockIdx.z == 0 ? w0 : (blockIdx.z == 1 ? w1 : w2);
  f16* out = wt + (size_t)blockIdx.z * OO * DD;
  __shared__ float t[64][65];
  int d0 = blockIdx.x * 64;  // grid.x = DD/64 = 16
  int o0 = blockIdx.y * 64;  // grid.y = OO/64 = 8
  int tid = threadIdx.x;
#pragma unroll
  for (int i = 0; i < 16; ++i) {
    int idx = i * 256 + tid;
    int r = idx >> 6, c = idx & 63;
    t[r][c] = w[(size_t)(d0 + r) * OO + (o0 + c)];
  }
  __syncthreads();
#pragma unroll
  for (int i = 0; i < 16; ++i) {
    int idx = i * 256 + tid;
    int r = idx >> 6, c = idx & 63;
    out[(size_t)(o0 + r) * DD + (d0 + c)] = (f16)t[c][r];
  }
}

// --------------- async global -> LDS, 16B per lane ------------------------
__device__ __forceinline__ void gload_lds16(const f16* g, f16* l) {
  __builtin_amdgcn_global_load_lds(
      (const __attribute__((address_space(1))) void*)g,
      (__attribute__((address_space(3))) void*)l, 16, 0, 0);
}

// --------------- GEMM, B-transposed form: C[m][n] = sum_k A[m][k]*B[n][k] --
// TM x 128 tile, BK=64, 256 threads (4 waves; wave owns (TM/2) x 64).
// MODE 0: C = acc*scale (OUT_T)
// MODE 1: C = (f16)exp2(acc*scale - shift)          [scores+exp fusion]
// MODE 2: C = acc * Linv[row]  (float out)          [PV with 1/l scaling]
template <int TM, int MODE, typename OUT_T>
__global__ __launch_bounds__(256) void gemm_t(
    const f16* __restrict__ A, const f16* __restrict__ B, OUT_T* __restrict__ C,
    const float* __restrict__ Linv, int M, int N, int K, int lda, int ldb,
    int ldc, long sAz, long sBz, long sCz, int linvStride, float scale,
    float shift) {
  A += (long)blockIdx.z * sAz;
  B += (long)blockIdx.z * sBz;
  C += (long)blockIdx.z * sCz;
  if (MODE == 2) Linv += (long)blockIdx.z * linvStride;
  int tn = N >> 7;
  int bm = (int)blockIdx.x / tn, bn = (int)blockIdx.x % tn;

  constexpr int MF = TM / 32;  // 4 for TM=128, 2 for TM=64
  __shared__ f16 As[TM * 64];
  __shared__ f16 Bs[128 * 64];

  int tid = threadIdx.x;
  int lane = tid & 63, wid = tid >> 6;
  int wr = (wid >> 1) * (MF * 16), wc = (wid & 1) << 6;

  f32x4 acc[MF][4] = {};

  const f16* Ag = A + (long)(bm * TM) * lda;
  const f16* Bg = B + (long)(bn * 128) * ldb;

  int r = lane & 15, g = lane >> 4;

  for (int k0 = 0; k0 < K; k0 += 64) {
#pragma unroll
    for (int i = 0; i < TM / 32; ++i) {
      int t = i * 256 + tid;
      gload_lds16(Ag + (long)(t >> 3) * lda + k0 + ((t & 7) << 3),
                  As + (i * 256 + (wid << 6)) * 8);
    }
#pragma unroll
    for (int i = 0; i < 4; ++i) {
      int t = i * 256 + tid;
      gload_lds16(Bg + (long)(t >> 3) * ldb + k0 + ((t & 7) << 3),
                  Bs + (i * 256 + (wid << 6)) * 8);
    }
    __syncthreads();
#pragma unroll
    for (int kk = 0; kk < 64; kk += 32) {
      f16x8 af[MF], bf[4];
#pragma unroll
      for (int m = 0; m < MF; ++m)
        af[m] = *(const f16x8*)&As[(wr + m * 16 + r) * 64 + kk + g * 8];
#pragma unroll
      for (int n = 0; n < 4; ++n)
        bf[n] = *(const f16x8*)&Bs[(wc + n * 16 + r) * 64 + kk + g * 8];
#pragma unroll
      for (int m = 0; m < MF; ++m)
#pragma unroll
        for (int n = 0; n < 4; ++n)
          acc[m][n] = __builtin_amdgcn_mfma_f32_16x16x32_f16(af[m], bf[n],
                                                             acc[m][n], 0, 0, 0);
    }
    __syncthreads();
  }

  float li[MF][4];
  if (MODE == 2) {
#pragma unroll
    for (int m = 0; m < MF; ++m)
#pragma unroll
      for (int j = 0; j < 4; ++j)
        li[m][j] = Linv[bm * TM + wr + m * 16 + g * 4 + j];
  }

#pragma unroll
  for (int m = 0; m < MF; ++m)
#pragma unroll
    for (int n = 0; n < 4; ++n)
#pragma unroll
      for (int j = 0; j < 4; ++j) {
        int row = bm * TM + wr + m * 16 + g * 4 + j;
        int col = bn * 128 + wc + n * 16 + r;
        float a = acc[m][n][j];
        if (MODE == 0)
          C[(long)row * ldc + col] = (OUT_T)(a * scale);
        else if (MODE == 1)
          C[(long)row * ldc + col] = (OUT_T)(f16)exp2f(a * scale - shift);
        else
          C[(long)row * ldc + col] = (OUT_T)(a * li[m][j]);
      }
}

// ------ row sum of P~ (f16, SS per row) -> Linv[row] = 1/sum (f32) --------
__global__ __launch_bounds__(256) void rowsum_inv(const f16* __restrict__ P,
                                                  float* __restrict__ Linv) {
  long row = blockIdx.x;  // 8192 rows
  const f16* p = P + row * SS;
  int tid = threadIdx.x;
  int lane = tid & 63, wid = tid >> 6;
  f16x8 v = *((const f16x8*)p + tid);
  float sum = 0.f;
#pragma unroll
  for (int j = 0; j < 8; ++j) sum += (float)v[j];
#pragma unroll
  for (int off = 32; off; off >>= 1) sum += __shfl_xor(sum, off);
  __shared__ float red[4];
  if (lane == 0) red[wid] = sum;
  __syncthreads();
  if (tid == 0) Linv[row] = 1.f / (red[0] + red[1] + red[2] + red[3]);
}

// ---------------------------------------------------------------------------
extern "C" void kernel_launch(void* const* d_in, const int* in_sizes, int n_in,
                              void* d_out, int out_size, void* d_ws,
                              size_t ws_size, hipStream_t stream) {
  const float* X = (const float*)d_in[0];
  const float* WQ = (const float*)d_in[1];
  const float* WK = (const float*)d_in[2];
  const float* WV = (const float*)d_in[3];
  float* out = (float*)d_out;

  char* ws = (char*)d_ws;
  f16* Xh = (f16*)ws;                       // 8192x1024 f16 = 16 MB
  f16* Wt = (f16*)(ws + 16777216);          // 3 x [512][1024] f16 = 3 MB
  f16* Qh = (f16*)(ws + 19922944);          // 8192x512 f16 = 8 MB
  f16* Kh = (f16*)(ws + 28311552);          // 8 MB (contiguous after Qh)
  f16* Vt = (f16*)(ws + 36700160);          // 4 x [512][2048] f16 = 8 MB
  f16* Pb = (f16*)(ws + 45088768);          // 4 x 2048x2048 f16 = 33.5 MB
  float* Linv = (float*)(ws + 78643200);    // 8192 f32 = 32 KB

  const float kScale = 0.044194173824159216f;   // 1/sqrt(512)
  const float kSclLog2e = kScale * 1.4426950408889634f;
  const float kShift = 12.0f * 1.4426950408889634f;

  // 1) convert X
  cvt_x<<<4096, 256, 0, stream>>>(X, Xh, 1048576);
  // 2) transpose-convert weights
  cvt_wt<<<dim3(16, 8, 3), 256, 0, stream>>>(WQ, WK, WV, Wt);
  // 3) Q,K projections: [8192,1024] @ Wt^T -> [8192,512], z in {Q,K}
  gemm_t<128, 0, f16><<<dim3(256, 1, 2), 256, 0, stream>>>(
      Xh, Wt, Qh, nullptr, 8192, 512, 1024, 1024, 1024, 512,
      0L, (long)OO * DD, (long)8192 * OO, 0, 1.f, 0.f);
  // 4) V^T projection per batch: WtV @ Xb^T -> Vt[b][512][2048]  (64-row tile)
  gemm_t<64, 0, f16><<<dim3(128, 1, 4), 256, 0, stream>>>(
      Wt + 2 * OO * DD, Xh, Vt, nullptr, 512, 2048, 1024, 1024, 1024, 2048,
      0L, (long)SS * DD, (long)OO * SS, 0, 1.f, 0.f);
  // 5) scores+exp per batch: P~ = exp2(QK^T * scl - shift) -> f16
  gemm_t<128, 1, f16><<<dim3(256, 1, 4), 256, 0, stream>>>(
      Qh, Kh, Pb, nullptr, 2048, 2048, 512, 512, 512, 2048,
      (long)SS * OO, (long)SS * OO, (long)SS * SS, 0, kSclLog2e, kShift);
  // 6) row sums -> Linv
  rowsum_inv<<<8192, 256, 0, stream>>>(Pb, Linv);
  // 7) out = (P~ @ V) * Linv[row]  (64-row tile, 512 blocks)
  gemm_t<64, 2, float><<<dim3(128, 1, 4), 256, 0, stream>>>(
      Pb, Vt, out, Linv, 2048, 512, 2048, 2048, 2048, 512,
      (long)SS * SS, (long)OO * SS, (long)SS * OO, SS, 1.f, 0.f);
}

// Round 3
// 124.997 us; speedup vs baseline: 1.3228x; 1.1646x over previous
//
#include <hip/hip_runtime.h>
#include <hip/hip_bf16.h>
#include <hip/hip_fp16.h>

typedef _Float16 f16;
typedef _Float16 f16x8 __attribute__((ext_vector_type(8)));
typedef float f32x4 __attribute__((ext_vector_type(4)));

#define NB 4
#define SS 2048
#define DD 1024
#define OO 512

// ---------------- convert X f32 -> f16 (vectorized, 8 elems/thread) -------
__global__ __launch_bounds__(256) void cvt_x(const float* __restrict__ x,
                                             f16* __restrict__ y, int n8) {
  int i = blockIdx.x * 256 + threadIdx.x;
  if (i >= n8) return;
  const float4* xp = (const float4*)x + (size_t)i * 2;
  float4 a = xp[0], b = xp[1];
  f16x8 v;
  v[0] = (f16)a.x; v[1] = (f16)a.y; v[2] = (f16)a.z; v[3] = (f16)a.w;
  v[4] = (f16)b.x; v[5] = (f16)b.y; v[6] = (f16)b.z; v[7] = (f16)b.w;
  *((f16x8*)y + i) = v;
}

// ------------- transpose-convert W [D][O] f32 -> Wt [O][D] f16 ------------
__global__ __launch_bounds__(256) void cvt_wt(const float* __restrict__ w0,
                                              const float* __restrict__ w1,
                                              const float* __restrict__ w2,
                                              f16* __restrict__ wt) {
  const float* w = blockIdx.z == 0 ? w0 : (blockIdx.z == 1 ? w1 : w2);
  f16* out = wt + (size_t)blockIdx.z * OO * DD;
  __shared__ float t[64][65];
  int d0 = blockIdx.x * 64;
  int o0 = blockIdx.y * 64;
  int tid = threadIdx.x;
#pragma unroll
  for (int i = 0; i < 16; ++i) {
    int idx = i * 256 + tid;
    int r = idx >> 6, c = idx & 63;
    t[r][c] = w[(size_t)(d0 + r) * OO + (o0 + c)];
  }
  __syncthreads();
#pragma unroll
  for (int i = 0; i < 16; ++i) {
    int idx = i * 256 + tid;
    int r = idx >> 6, c = idx & 63;
    out[(size_t)(o0 + r) * DD + (d0 + c)] = (f16)t[c][r];
  }
}

// --------------- async global -> LDS, 16B per lane ------------------------
__device__ __forceinline__ void gload_lds16(const f16* g, f16* l) {
  __builtin_amdgcn_global_load_lds(
      (const __attribute__((address_space(1))) void*)g,
      (__attribute__((address_space(3))) void*)l, 16, 0, 0);
}

// counted vmcnt wait: leave fut*LPI loads outstanding (immediates only)
template <int LPI>
__device__ __forceinline__ void wait_fut(int fut) {
  if constexpr (LPI == 6) {  // TM=64, RING=3
    if (fut >= 2) asm volatile("s_waitcnt vmcnt(12)" ::: "memory");
    else if (fut == 1) asm volatile("s_waitcnt vmcnt(6)" ::: "memory");
    else asm volatile("s_waitcnt vmcnt(0)" ::: "memory");
  } else {  // LPI==8: TM=128, RING=2
    if (fut >= 1) asm volatile("s_waitcnt vmcnt(8)" ::: "memory");
    else asm volatile("s_waitcnt vmcnt(0)" ::: "memory");
  }
}

// --------------- GEMM, B-transposed form: C[m][n] = sum_k A[m][k]*B[n][k] --
// TM x 128 tile, BK=64, 256 threads (4 waves; wave owns (TM/2) x 64).
// Ring-buffered staging (counted vmcnt, raw barriers) + XOR-swizzled LDS
// (linear gload_lds dest, pre-swizzled global source, swizzled ds_read).
// MODE 0: C = acc (OUT_T)
// MODE 1: C = (f16)exp2(acc*scale - shift); atomicAdd row sums into L
// MODE 2: C = acc / L[row]  (float out)
template <int TM, int RING, int MODE, typename OUT_T>
__global__ __launch_bounds__(256) void gemm_t(
    const f16* __restrict__ A, const f16* __restrict__ B, OUT_T* __restrict__ C,
    float* __restrict__ L, int N, int K, int lda, int ldb, int ldc,
    long sAz, long sBz, long sCz, int lStride, float scale, float shift) {
  A += (long)blockIdx.z * sAz;
  B += (long)blockIdx.z * sBz;
  C += (long)blockIdx.z * sCz;
  if (MODE != 0) L += (long)blockIdx.z * lStride;

  constexpr int MF = TM / 32;        // m-fragments per wave
  constexpr int LPI = TM / 32 + 4;   // gload_lds per thread per K-step
  constexpr int SLOT = (TM + 128) * 64;
  __shared__ f16 ring[RING * SLOT];

  int tid = threadIdx.x;
  int lane = tid & 63, wid = tid >> 6;
  int wr = (wid >> 1) * (MF * 16), wc = (wid & 1) << 6;
  int r = lane & 15, g = lane >> 4;
  int tn = N >> 7;
  int bm = (int)blockIdx.x / tn, bn = (int)blockIdx.x % tn;

  const f16* Ag = A + (long)(bm * TM) * lda;
  const f16* Bg = B + (long)(bn * 128) * ldb;

  int srow = wid * 8 + (lane >> 3);                    // row within 32-chunk
  int scol = (((lane & 7) ^ ((lane >> 3) & 7)) << 3);  // pre-swizzled col

  f32x4 acc[MF][4] = {};
  int nt = K >> 6;

  auto stage = [&](int si, int k0) {
    f16* s = ring + si * SLOT;
#pragma unroll
    for (int i = 0; i < TM / 32; ++i)
      gload_lds16(Ag + (long)(i * 32 + srow) * lda + k0 + scol,
                  s + i * 2048 + wid * 512);
#pragma unroll
    for (int i = 0; i < 4; ++i)
      gload_lds16(Bg + (long)(i * 32 + srow) * ldb + k0 + scol,
                  s + TM * 64 + i * 2048 + wid * 512);
  };

  for (int p = 0; p < RING && p < nt; ++p) stage(p, p * 64);

  int rb = 0;
  for (int t = 0; t < nt; ++t) {
    int fut = nt - 1 - t;
    if (fut > RING - 1) fut = RING - 1;
    wait_fut<LPI>(fut);
    __builtin_amdgcn_s_barrier();
    __builtin_amdgcn_sched_barrier(0);
    const f16* sa = ring + rb * SLOT;
    const f16* sb = sa + TM * 64;
#pragma unroll
    for (int kk = 0; kk < 64; kk += 32) {
      f16x8 af[MF], bf[4];
      int xo = ((kk * 2 + g * 16) ^ ((r & 7) << 4)) >> 1;  // swizzled elem off
#pragma unroll
      for (int m = 0; m < MF; ++m)
        af[m] = *(const f16x8*)&sa[(wr + m * 16 + r) * 64 + xo];
#pragma unroll
      for (int n = 0; n < 4; ++n)
        bf[n] = *(const f16x8*)&sb[(wc + n * 16 + r) * 64 + xo];
#pragma unroll
      for (int m = 0; m < MF; ++m)
#pragma unroll
        for (int n = 0; n < 4; ++n)
          acc[m][n] = __builtin_amdgcn_mfma_f32_16x16x32_f16(af[m], bf[n],
                                                             acc[m][n], 0, 0, 0);
    }
    __builtin_amdgcn_s_barrier();
    __builtin_amdgcn_sched_barrier(0);
    if (t + RING < nt) stage(rb, (t + RING) * 64);
    rb = (rb + 1 == RING) ? 0 : rb + 1;
  }

  if (MODE == 1) {
    float rs[MF][4];
#pragma unroll
    for (int m = 0; m < MF; ++m)
#pragma unroll
      for (int j = 0; j < 4; ++j) rs[m][j] = 0.f;
#pragma unroll
    for (int m = 0; m < MF; ++m)
#pragma unroll
      for (int n = 0; n < 4; ++n)
#pragma unroll
        for (int j = 0; j < 4; ++j) {
          int row = bm * TM + wr + m * 16 + g * 4 + j;
          int col = bn * 128 + wc + n * 16 + r;
          float e = exp2f(acc[m][n][j] * scale - shift);
          C[(long)row * ldc + col] = (OUT_T)(f16)e;
          rs[m][j] += e;
        }
#pragma unroll
    for (int m = 0; m < MF; ++m)
#pragma unroll
      for (int j = 0; j < 4; ++j) {
        float v = rs[m][j];
        v += __shfl_xor(v, 1);
        v += __shfl_xor(v, 2);
        v += __shfl_xor(v, 4);
        v += __shfl_xor(v, 8);
        if (r == 0) atomicAdd(&L[bm * TM + wr + m * 16 + g * 4 + j], v);
      }
  } else if (MODE == 2) {
    float li[MF][4];
#pragma unroll
    for (int m = 0; m < MF; ++m)
#pragma unroll
      for (int j = 0; j < 4; ++j)
        li[m][j] = 1.0f / L[bm * TM + wr + m * 16 + g * 4 + j];
#pragma unroll
    for (int m = 0; m < MF; ++m)
#pragma unroll
      for (int n = 0; n < 4; ++n)
#pragma unroll
        for (int j = 0; j < 4; ++j) {
          int row = bm * TM + wr + m * 16 + g * 4 + j;
          int col = bn * 128 + wc + n * 16 + r;
          C[(long)row * ldc + col] = (OUT_T)(acc[m][n][j] * li[m][j]);
        }
  } else {
#pragma unroll
    for (int m = 0; m < MF; ++m)
#pragma unroll
      for (int n = 0; n < 4; ++n)
#pragma unroll
        for (int j = 0; j < 4; ++j) {
          int row = bm * TM + wr + m * 16 + g * 4 + j;
          int col = bn * 128 + wc + n * 16 + r;
          C[(long)row * ldc + col] = (OUT_T)(acc[m][n][j] * scale);
        }
  }
}

// ---------------------------------------------------------------------------
extern "C" void kernel_launch(void* const* d_in, const int* in_sizes, int n_in,
                              void* d_out, int out_size, void* d_ws,
                              size_t ws_size, hipStream_t stream) {
  const float* X = (const float*)d_in[0];
  const float* WQ = (const float*)d_in[1];
  const float* WK = (const float*)d_in[2];
  const float* WV = (const float*)d_in[3];
  float* out = (float*)d_out;

  char* ws = (char*)d_ws;
  f16* Xh = (f16*)ws;                       // 8192x1024 f16 = 16 MB
  f16* Wt = (f16*)(ws + 16777216);          // 3 x [512][1024] f16 = 3 MB
  f16* Qh = (f16*)(ws + 19922944);          // 8192x512 f16 = 8 MB
  f16* Kh = (f16*)(ws + 28311552);          // 8 MB
  f16* Vt = (f16*)(ws + 36700160);          // 4 x [512][2048] f16 = 8 MB
  f16* Pb = (f16*)(ws + 45088768);          // 4 x 2048x2048 f16 = 33.5 MB
  float* Ls = (float*)(ws + 78643200);      // 4 x 2048 f32 row sums = 32 KB

  const float kScale = 0.044194173824159216f;  // 1/sqrt(512)
  const float kSclLog2e = kScale * 1.4426950408889634f;
  const float kShift = 12.0f * 1.4426950408889634f;

  hipMemsetAsync(Ls, 0, NB * SS * sizeof(float), stream);
  // 1) convert X
  cvt_x<<<4096, 256, 0, stream>>>(X, Xh, 1048576);
  // 2) transpose-convert weights
  cvt_wt<<<dim3(16, 8, 3), 256, 0, stream>>>(WQ, WK, WV, Wt);
  // 3) Q,K projections: [8192,1024] @ Wt^T -> [8192,512], z in {Q,K}
  gemm_t<128, 2, 0, f16><<<dim3(256, 1, 2), 256, 0, stream>>>(
      Xh, Wt, Qh, nullptr, 512, 1024, 1024, 1024, 512,
      0L, (long)OO * DD, (long)8192 * OO, 0, 1.f, 0.f);
  // 4) V^T projection per batch: WtV @ Xb^T -> Vt[b][512][2048]
  gemm_t<64, 3, 0, f16><<<dim3(128, 1, 4), 256, 0, stream>>>(
      Wt + 2 * OO * DD, Xh, Vt, nullptr, 2048, 1024, 1024, 1024, 2048,
      0L, (long)SS * DD, (long)OO * SS, 0, 1.f, 0.f);
  // 5) scores+exp per batch: P~ = exp2(QK^T*scl - shift) -> f16, rowsums -> Ls
  gemm_t<128, 2, 1, f16><<<dim3(256, 1, 4), 256, 0, stream>>>(
      Qh, Kh, Pb, Ls, 2048, 512, 512, 512, 2048,
      (long)SS * OO, (long)SS * OO, (long)SS * SS, SS, kSclLog2e, kShift);
  // 6) out = (P~ @ V) / Ls[row]
  gemm_t<64, 3, 2, float><<<dim3(128, 1, 4), 256, 0, stream>>>(
      Pb, Vt, out, Ls, 512, 2048, 2048, 2048, 512,
      (long)SS * SS, (long)OO * SS, (long)SS * OO, SS, 1.f, 0.f);
}

// Round 4
// 120.424 us; speedup vs baseline: 1.3730x; 1.0380x over previous
//
#include <hip/hip_runtime.h>
#include <hip/hip_bf16.h>
#include <hip/hip_fp16.h>

typedef _Float16 f16;
typedef _Float16 f16x8 __attribute__((ext_vector_type(8)));
typedef float f32x4 __attribute__((ext_vector_type(4)));

#define NB 4
#define SS 2048
#define DD 1024
#define OO 512

// ------- convert X f32 -> f16 (8 elems/thread) + zero the L buffer --------
// grid.x = 4096 convert blocks + 32 zeroing blocks (NB*SS floats = 8192).
__global__ __launch_bounds__(256) void cvt_x(const float* __restrict__ x,
                                             f16* __restrict__ y, int n8,
                                             float* __restrict__ Ls) {
  int b = blockIdx.x;
  if (b >= 4096) {
    int i = (b - 4096) * 256 + threadIdx.x;
    Ls[i] = 0.f;
    return;
  }
  int i = b * 256 + threadIdx.x;
  if (i >= n8) return;
  const float4* xp = (const float4*)x + (size_t)i * 2;
  float4 a = xp[0], c = xp[1];
  f16x8 v;
  v[0] = (f16)a.x; v[1] = (f16)a.y; v[2] = (f16)a.z; v[3] = (f16)a.w;
  v[4] = (f16)c.x; v[5] = (f16)c.y; v[6] = (f16)c.z; v[7] = (f16)c.w;
  *((f16x8*)y + i) = v;
}

// ------------- transpose-convert W [D][O] f32 -> Wt [O][D] f16 ------------
__global__ __launch_bounds__(256) void cvt_wt(const float* __restrict__ w0,
                                              const float* __restrict__ w1,
                                              const float* __restrict__ w2,
                                              f16* __restrict__ wt) {
  const float* w = blockIdx.z == 0 ? w0 : (blockIdx.z == 1 ? w1 : w2);
  f16* out = wt + (size_t)blockIdx.z * OO * DD;
  __shared__ float t[64][65];
  int d0 = blockIdx.x * 64;
  int o0 = blockIdx.y * 64;
  int tid = threadIdx.x;
#pragma unroll
  for (int i = 0; i < 16; ++i) {
    int idx = i * 256 + tid;
    int r = idx >> 6, c = idx & 63;
    t[r][c] = w[(size_t)(d0 + r) * OO + (o0 + c)];
  }
  __syncthreads();
#pragma unroll
  for (int i = 0; i < 16; ++i) {
    int idx = i * 256 + tid;
    int r = idx >> 6, c = idx & 63;
    out[(size_t)(o0 + r) * DD + (d0 + c)] = (f16)t[c][r];
  }
}

// --------------- async global -> LDS, 16B per lane ------------------------
__device__ __forceinline__ void gload_lds16(const f16* g, f16* l) {
  __builtin_amdgcn_global_load_lds(
      (const __attribute__((address_space(1))) void*)g,
      (__attribute__((address_space(3))) void*)l, 16, 0, 0);
}

// counted vmcnt wait: leave fut*LPI loads outstanding (immediates only)
template <int LPI>
__device__ __forceinline__ void wait_fut(int fut) {
  if constexpr (LPI == 6) {  // TM=64, RING=3
    if (fut >= 2) asm volatile("s_waitcnt vmcnt(12)" ::: "memory");
    else if (fut == 1) asm volatile("s_waitcnt vmcnt(6)" ::: "memory");
    else asm volatile("s_waitcnt vmcnt(0)" ::: "memory");
  } else {  // LPI==8: TM=128, RING=2
    if (fut >= 1) asm volatile("s_waitcnt vmcnt(8)" ::: "memory");
    else asm volatile("s_waitcnt vmcnt(0)" ::: "memory");
  }
}

// --------------- GEMM, B-transposed form: C[m][n] = sum_k A[m][k]*B[n][k] --
// TM x 128 tile, BK=64, 256 threads (4 waves; wave owns (TM/2) x 64).
// Ring-buffered staging (counted vmcnt, raw barriers) + XOR-swizzled LDS
// (linear gload_lds dest, pre-swizzled global source, swizzled ds_read).
// MODE 0: C = acc (OUT_T)
// MODE 1: C = (f16)exp2(acc*scale - shift); atomicAdd row sums into L
// MODE 2: C = acc / L[row]  (float out)
template <int TM, int RING, int MODE, typename OUT_T>
__global__ __launch_bounds__(256) void gemm_t(
    const f16* __restrict__ A, const f16* __restrict__ B, OUT_T* __restrict__ C,
    float* __restrict__ L, int N, int K, int lda, int ldb, int ldc,
    long sAz, long sBz, long sCz, int lStride, float scale, float shift) {
  A += (long)blockIdx.z * sAz;
  B += (long)blockIdx.z * sBz;
  C += (long)blockIdx.z * sCz;
  if (MODE != 0) L += (long)blockIdx.z * lStride;

  constexpr int MF = TM / 32;        // m-fragments per wave
  constexpr int LPI = TM / 32 + 4;   // gload_lds per thread per K-step
  constexpr int SLOT = (TM + 128) * 64;
  __shared__ f16 ring[RING * SLOT];

  int tid = threadIdx.x;
  int lane = tid & 63, wid = tid >> 6;
  int wr = (wid >> 1) * (MF * 16), wc = (wid & 1) << 6;
  int r = lane & 15, g = lane >> 4;
  int tn = N >> 7;
  int bm = (int)blockIdx.x / tn, bn = (int)blockIdx.x % tn;

  const f16* Ag = A + (long)(bm * TM) * lda;
  const f16* Bg = B + (long)(bn * 128) * ldb;

  int srow = wid * 8 + (lane >> 3);                    // row within 32-chunk
  int scol = (((lane & 7) ^ ((lane >> 3) & 7)) << 3);  // pre-swizzled col

  f32x4 acc[MF][4] = {};
  int nt = K >> 6;

  auto stage = [&](int si, int k0) {
    f16* s = ring + si * SLOT;
#pragma unroll
    for (int i = 0; i < TM / 32; ++i)
      gload_lds16(Ag + (long)(i * 32 + srow) * lda + k0 + scol,
                  s + i * 2048 + wid * 512);
#pragma unroll
    for (int i = 0; i < 4; ++i)
      gload_lds16(Bg + (long)(i * 32 + srow) * ldb + k0 + scol,
                  s + TM * 64 + i * 2048 + wid * 512);
  };

  for (int p = 0; p < RING && p < nt; ++p) stage(p, p * 64);

  int rb = 0;
  for (int t = 0; t < nt; ++t) {
    int fut = nt - 1 - t;
    if (fut > RING - 1) fut = RING - 1;
    wait_fut<LPI>(fut);
    __builtin_amdgcn_s_barrier();
    __builtin_amdgcn_sched_barrier(0);
    const f16* sa = ring + rb * SLOT;
    const f16* sb = sa + TM * 64;
#pragma unroll
    for (int kk = 0; kk < 64; kk += 32) {
      f16x8 af[MF], bf[4];
      int xo = ((kk * 2 + g * 16) ^ ((r & 7) << 4)) >> 1;  // swizzled elem off
#pragma unroll
      for (int m = 0; m < MF; ++m)
        af[m] = *(const f16x8*)&sa[(wr + m * 16 + r) * 64 + xo];
#pragma unroll
      for (int n = 0; n < 4; ++n)
        bf[n] = *(const f16x8*)&sb[(wc + n * 16 + r) * 64 + xo];
#pragma unroll
      for (int m = 0; m < MF; ++m)
#pragma unroll
        for (int n = 0; n < 4; ++n)
          acc[m][n] = __builtin_amdgcn_mfma_f32_16x16x32_f16(af[m], bf[n],
                                                             acc[m][n], 0, 0, 0);
    }
    __builtin_amdgcn_s_barrier();
    __builtin_amdgcn_sched_barrier(0);
    if (t + RING < nt) stage(rb, (t + RING) * 64);
    rb = (rb + 1 == RING) ? 0 : rb + 1;
  }

  if (MODE == 1) {
    float rs[MF][4];
#pragma unroll
    for (int m = 0; m < MF; ++m)
#pragma unroll
      for (int j = 0; j < 4; ++j) rs[m][j] = 0.f;
#pragma unroll
    for (int m = 0; m < MF; ++m)
#pragma unroll
      for (int n = 0; n < 4; ++n)
#pragma unroll
        for (int j = 0; j < 4; ++j) {
          int row = bm * TM + wr + m * 16 + g * 4 + j;
          int col = bn * 128 + wc + n * 16 + r;
          float e = exp2f(acc[m][n][j] * scale - shift);
          C[(long)row * ldc + col] = (OUT_T)(f16)e;
          rs[m][j] += e;
        }
#pragma unroll
    for (int m = 0; m < MF; ++m)
#pragma unroll
      for (int j = 0; j < 4; ++j) {
        float v = rs[m][j];
        v += __shfl_xor(v, 1);
        v += __shfl_xor(v, 2);
        v += __shfl_xor(v, 4);
        v += __shfl_xor(v, 8);
        if (r == 0) atomicAdd(&L[bm * TM + wr + m * 16 + g * 4 + j], v);
      }
  } else if (MODE == 2) {
    float li[MF][4];
#pragma unroll
    for (int m = 0; m < MF; ++m)
#pragma unroll
      for (int j = 0; j < 4; ++j)
        li[m][j] = 1.0f / L[bm * TM + wr + m * 16 + g * 4 + j];
#pragma unroll
    for (int m = 0; m < MF; ++m)
#pragma unroll
      for (int n = 0; n < 4; ++n)
#pragma unroll
        for (int j = 0; j < 4; ++j) {
          int row = bm * TM + wr + m * 16 + g * 4 + j;
          int col = bn * 128 + wc + n * 16 + r;
          C[(long)row * ldc + col] = (OUT_T)(acc[m][n][j] * li[m][j]);
        }
  } else {
#pragma unroll
    for (int m = 0; m < MF; ++m)
#pragma unroll
      for (int n = 0; n < 4; ++n)
#pragma unroll
        for (int j = 0; j < 4; ++j) {
          int row = bm * TM + wr + m * 16 + g * 4 + j;
          int col = bn * 128 + wc + n * 16 + r;
          C[(long)row * ldc + col] = (OUT_T)(acc[m][n][j] * scale);
        }
  }
}

// ---------------------------------------------------------------------------
extern "C" void kernel_launch(void* const* d_in, const int* in_sizes, int n_in,
                              void* d_out, int out_size, void* d_ws,
                              size_t ws_size, hipStream_t stream) {
  const float* X = (const float*)d_in[0];
  const float* WQ = (const float*)d_in[1];
  const float* WK = (const float*)d_in[2];
  const float* WV = (const float*)d_in[3];
  float* out = (float*)d_out;

  char* ws = (char*)d_ws;
  f16* Xh = (f16*)ws;                       // 8192x1024 f16 = 16 MB
  f16* Wt = (f16*)(ws + 16777216);          // 3 x [512][1024] f16 = 3 MB
  f16* Qh = (f16*)(ws + 19922944);          // 8192x512 f16 = 8 MB
  f16* Kh = (f16*)(ws + 28311552);          // 8 MB
  f16* Vt = (f16*)(ws + 36700160);          // 4 x [512][2048] f16 = 8 MB
  f16* Pb = (f16*)(ws + 45088768);          // 4 x 2048x2048 f16 = 33.5 MB
  float* Ls = (float*)(ws + 78643200);      // 4 x 2048 f32 row sums = 32 KB

  const float kScale = 0.044194173824159216f;  // 1/sqrt(512)
  const float kSclLog2e = kScale * 1.4426950408889634f;
  const float kShift = 12.0f * 1.4426950408889634f;

  // 1) convert X (+ zero Ls in the 32 tail blocks)
  cvt_x<<<4128, 256, 0, stream>>>(X, Xh, 1048576, Ls);
  // 2) transpose-convert weights
  cvt_wt<<<dim3(16, 8, 3), 256, 0, stream>>>(WQ, WK, WV, Wt);
  // 3) Q,K projections: [8192,1024] @ Wt^T -> [8192,512], z in {Q,K}
  gemm_t<128, 2, 0, f16><<<dim3(256, 1, 2), 256, 0, stream>>>(
      Xh, Wt, Qh, nullptr, 512, 1024, 1024, 1024, 512,
      0L, (long)OO * DD, (long)8192 * OO, 0, 1.f, 0.f);
  // 4) V^T projection per batch: WtV @ Xb^T -> Vt[b][512][2048]
  gemm_t<64, 3, 0, f16><<<dim3(128, 1, 4), 256, 0, stream>>>(
      Wt + 2 * OO * DD, Xh, Vt, nullptr, 2048, 1024, 1024, 1024, 2048,
      0L, (long)SS * DD, (long)OO * SS, 0, 1.f, 0.f);
  // 5) scores+exp per batch: P~ = exp2(QK^T*scl - shift) -> f16, rowsums -> Ls
  gemm_t<128, 2, 1, f16><<<dim3(256, 1, 4), 256, 0, stream>>>(
      Qh, Kh, Pb, Ls, 2048, 512, 512, 512, 2048,
      (long)SS * OO, (long)SS * OO, (long)SS * SS, SS, kSclLog2e, kShift);
  // 6) out = (P~ @ V) / Ls[row]
  gemm_t<64, 3, 2, float><<<dim3(128, 1, 4), 256, 0, stream>>>(
      Pb, Vt, out, Ls, 512, 2048, 2048, 2048, 512,
      (long)SS * SS, (long)OO * SS, (long)SS * OO, SS, 1.f, 0.f);
}

// Round 5
// 103.807 us; speedup vs baseline: 1.5928x; 1.1601x over previous
//
#include <hip/hip_runtime.h>
#include <hip/hip_bf16.h>
#include <hip/hip_fp16.h>

typedef _Float16 f16;
typedef _Float16 f16x8 __attribute__((ext_vector_type(8)));
typedef float f32x4 __attribute__((ext_vector_type(4)));

#define NB 4
#define SS 2048
#define DD 1024
#define OO 512

// ---- prep: cvt X f32->f16 | transpose-cvt W | zero Ls  (flat grid 4512) ---
__global__ __launch_bounds__(256) void prep(const float* __restrict__ X,
                                            f16* __restrict__ Xh,
                                            const float* __restrict__ w0,
                                            const float* __restrict__ w1,
                                            const float* __restrict__ w2,
                                            f16* __restrict__ Wt,
                                            float* __restrict__ Ls) {
  int b = blockIdx.x;
  int tid = threadIdx.x;
  if (b < 4096) {
    int i = b * 256 + tid;
    const float4* xp = (const float4*)X + (size_t)i * 2;
    float4 a = xp[0], c = xp[1];
    f16x8 v;
    v[0] = (f16)a.x; v[1] = (f16)a.y; v[2] = (f16)a.z; v[3] = (f16)a.w;
    v[4] = (f16)c.x; v[5] = (f16)c.y; v[6] = (f16)c.z; v[7] = (f16)c.w;
    *((f16x8*)Xh + i) = v;
  } else if (b < 4480) {
    int rem = b - 4096;                 // 0..383
    int z = rem >> 7;                   // 0..2
    int rem2 = rem & 127;
    int d0 = (rem2 >> 3) * 64;          // 0..15 -> D blocks
    int o0 = (rem2 & 7) * 64;           // 0..7  -> O blocks
    const float* w = z == 0 ? w0 : (z == 1 ? w1 : w2);
    f16* out = Wt + (size_t)z * OO * DD;
    __shared__ float t[64][65];
#pragma unroll
    for (int i = 0; i < 16; ++i) {
      int idx = i * 256 + tid;
      int r = idx >> 6, c = idx & 63;
      t[r][c] = w[(size_t)(d0 + r) * OO + (o0 + c)];
    }
    __syncthreads();
#pragma unroll
    for (int i = 0; i < 16; ++i) {
      int idx = i * 256 + tid;
      int r = idx >> 6, c = idx & 63;
      out[(size_t)(o0 + r) * DD + (d0 + c)] = (f16)t[c][r];
    }
  } else {
    Ls[(b - 4480) * 256 + tid] = 0.f;
  }
}

// --------------- async global -> LDS, 16B per lane ------------------------
__device__ __forceinline__ void gload_lds16(const f16* g, f16* l) {
  __builtin_amdgcn_global_load_lds(
      (const __attribute__((address_space(1))) void*)g,
      (__attribute__((address_space(3))) void*)l, 16, 0, 0);
}

// counted vmcnt wait: leave fut*LPI loads outstanding (immediates only)
template <int LPI>
__device__ __forceinline__ void wait_fut(int fut) {
  if constexpr (LPI == 6) {  // TM=64, RING=3
    if (fut >= 2) asm volatile("s_waitcnt vmcnt(12)" ::: "memory");
    else if (fut == 1) asm volatile("s_waitcnt vmcnt(6)" ::: "memory");
    else asm volatile("s_waitcnt vmcnt(0)" ::: "memory");
  } else {  // LPI==8: RING=2 (both 128x128/256thr and 256x256/512thr)
    if (fut >= 1) asm volatile("s_waitcnt vmcnt(8)" ::: "memory");
    else asm volatile("s_waitcnt vmcnt(0)" ::: "memory");
  }
}

// ---- GEMM body, B-transposed: C[m][n] = sum_k A[m][k]*B[n][k] -------------
// TM x 128 tile, BK=64, 256 threads (4 waves). Ring staging (counted vmcnt,
// raw barriers) + XOR-swizzled LDS.
// MODE 0: C = (OUT_T)(acc*scale);  MODE 2: C = acc / L[row] (float out)
template <int TM, int RING, int MODE, typename OUT_T>
__device__ __forceinline__ void gemm_body(const f16* __restrict__ A,
                                          const f16* __restrict__ B,
                                          OUT_T* __restrict__ C,
                                          const float* __restrict__ L, int bm,
                                          int bn, int K, int lda, int ldb,
                                          int ldc, float scale) {
  constexpr int MF = TM / 32;
  constexpr int LPI = TM / 32 + 4;
  constexpr int SLOT = (TM + 128) * 64;
  __shared__ f16 ring[RING * SLOT];

  int tid = threadIdx.x;
  int lane = tid & 63, wid = tid >> 6;
  int wr = (wid >> 1) * (MF * 16), wc = (wid & 1) << 6;
  int r = lane & 15, g = lane >> 4;

  const f16* Ag = A + (long)(bm * TM) * lda;
  const f16* Bg = B + (long)(bn * 128) * ldb;

  int srow = wid * 8 + (lane >> 3);
  int scol = (((lane & 7) ^ ((lane >> 3) & 7)) << 3);

  f32x4 acc[MF][4] = {};
  int nt = K >> 6;

  auto stage = [&](int si, int k0) {
    f16* s = ring + si * SLOT;
#pragma unroll
    for (int i = 0; i < TM / 32; ++i)
      gload_lds16(Ag + (long)(i * 32 + srow) * lda + k0 + scol,
                  s + i * 2048 + wid * 512);
#pragma unroll
    for (int i = 0; i < 4; ++i)
      gload_lds16(Bg + (long)(i * 32 + srow) * ldb + k0 + scol,
                  s + TM * 64 + i * 2048 + wid * 512);
  };

  for (int p = 0; p < RING && p < nt; ++p) stage(p, p * 64);

  int rb = 0;
  for (int t = 0; t < nt; ++t) {
    int fut = nt - 1 - t;
    if (fut > RING - 1) fut = RING - 1;
    wait_fut<LPI>(fut);
    __builtin_amdgcn_s_barrier();
    __builtin_amdgcn_sched_barrier(0);
    const f16* sa = ring + rb * SLOT;
    const f16* sb = sa + TM * 64;
#pragma unroll
    for (int kk = 0; kk < 64; kk += 32) {
      f16x8 af[MF], bf[4];
      int xo = ((kk * 2 + g * 16) ^ ((r & 7) << 4)) >> 1;
#pragma unroll
      for (int m = 0; m < MF; ++m)
        af[m] = *(const f16x8*)&sa[(wr + m * 16 + r) * 64 + xo];
#pragma unroll
      for (int n = 0; n < 4; ++n)
        bf[n] = *(const f16x8*)&sb[(wc + n * 16 + r) * 64 + xo];
#pragma unroll
      for (int m = 0; m < MF; ++m)
#pragma unroll
        for (int n = 0; n < 4; ++n)
          acc[m][n] = __builtin_amdgcn_mfma_f32_16x16x32_f16(af[m], bf[n],
                                                             acc[m][n], 0, 0, 0);
    }
    __builtin_amdgcn_s_barrier();
    __builtin_amdgcn_sched_barrier(0);
    if (t + RING < nt) stage(rb, (t + RING) * 64);
    rb = (rb + 1 == RING) ? 0 : rb + 1;
  }

  if (MODE == 2) {
    float li[MF][4];
#pragma unroll
    for (int m = 0; m < MF; ++m)
#pragma unroll
      for (int j = 0; j < 4; ++j)
        li[m][j] = 1.0f / L[bm * TM + wr + m * 16 + g * 4 + j];
#pragma unroll
    for (int m = 0; m < MF; ++m)
#pragma unroll
      for (int n = 0; n < 4; ++n)
#pragma unroll
        for (int j = 0; j < 4; ++j) {
          int row = bm * TM + wr + m * 16 + g * 4 + j;
          int col = bn * 128 + wc + n * 16 + r;
          C[(long)row * ldc + col] = (OUT_T)(acc[m][n][j] * li[m][j]);
        }
  } else {
#pragma unroll
    for (int m = 0; m < MF; ++m)
#pragma unroll
      for (int n = 0; n < 4; ++n)
#pragma unroll
        for (int j = 0; j < 4; ++j) {
          int row = bm * TM + wr + m * 16 + g * 4 + j;
          int col = bn * 128 + wc + n * 16 + r;
          C[(long)row * ldc + col] = (OUT_T)(acc[m][n][j] * scale);
        }
  }
}

// ---- merged QKV projections: flat grid 768 -------------------------------
// id<512: QK proj (z=id>>8): Xh[8192,1024] @ Wt_z^T -> Qh/Kh [8192,512]
// id>=512: V proj (z): Wt_V[512,1024] @ Xh_z^T -> Vt[z][512][2048]
__global__ __launch_bounds__(256) void proj_qkv(const f16* __restrict__ Xh,
                                                const f16* __restrict__ Wt,
                                                f16* __restrict__ Qh,
                                                f16* __restrict__ Vt) {
  int id = blockIdx.x;
  if (id < 512) {
    int z = id >> 8, xid = id & 255;
    xid = (xid & 7) * 32 + (xid >> 3);  // XCD swizzle, 256 blocks
    int bm = xid >> 2, bn = xid & 3;
    gemm_body<128, 2, 0, f16>(Xh, Wt + (long)z * OO * DD,
                              Qh + (long)z * 8192 * OO, nullptr, bm, bn, DD,
                              DD, DD, OO, 1.f);
  } else {
    int rem = id - 512;
    int z = rem >> 6, xid = rem & 63;
    xid = (xid & 7) * 8 + (xid >> 3);  // XCD swizzle, 64 blocks
    int bm = xid >> 4, bn = xid & 15;
    gemm_body<128, 2, 0, f16>(Wt + 2L * OO * DD, Xh + (long)z * SS * DD,
                              Vt + (long)z * OO * SS, nullptr, bm, bn, DD, DD,
                              DD, SS, 1.f);
  }
}

// ---- scores256: 256x256 tile, 8 waves, P~=exp2(QK^T*scl-shift), rowsums ---
__global__ __launch_bounds__(512) void scores256(const f16* __restrict__ Q,
                                                 const f16* __restrict__ Kh,
                                                 f16* __restrict__ P,
                                                 float* __restrict__ L,
                                                 float scale, float shift) {
  int z = blockIdx.z;
  const f16* A = Q + (long)z * SS * OO;
  const f16* B = Kh + (long)z * SS * OO;
  f16* C = P + (long)z * SS * SS;
  float* Ls = L + (long)z * SS;
  int xid = blockIdx.x;              // 64 blocks
  xid = (xid & 7) * 8 + (xid >> 3);  // XCD swizzle
  int bm = xid >> 3, bn = xid & 7;

  __shared__ f16 ring[2 * 32768];  // 128 KB
  int tid = threadIdx.x;
  int lane = tid & 63, wid = tid >> 6;
  int wm = wid >> 2, wn = wid & 3;  // 2M x 4N waves
  int r = lane & 15, g = lane >> 4;

  const f16* Ag = A + (long)(bm * 256) * OO;
  const f16* Bg = B + (long)(bn * 256) * OO;

  int srow = tid >> 3;  // 0..63
  int scol = (((tid & 7) ^ ((tid >> 3) & 7)) << 3);

  f32x4 acc[8][4] = {};
  const int nt = OO / 64;  // 8

  auto stage = [&](int si, int k0) {
    f16* s = ring + si * 32768;
#pragma unroll
    for (int i = 0; i < 4; ++i)
      gload_lds16(Ag + (long)(i * 64 + srow) * OO + k0 + scol,
                  s + i * 4096 + tid * 8);
#pragma unroll
    for (int i = 0; i < 4; ++i)
      gload_lds16(Bg + (long)(i * 64 + srow) * OO + k0 + scol,
                  s + 16384 + i * 4096 + tid * 8);
  };
  stage(0, 0);
  stage(1, 64);
  int rb = 0;
  for (int t = 0; t < nt; ++t) {
    int fut = nt - 1 - t;
    if (fut > 1) fut = 1;
    wait_fut<8>(fut);
    __builtin_amdgcn_s_barrier();
    __builtin_amdgcn_sched_barrier(0);
    const f16* sa = ring + rb * 32768;
    const f16* sb = sa + 16384;
#pragma unroll
    for (int kk = 0; kk < 64; kk += 32) {
      f16x8 af[8], bf[4];
      int xo = ((kk * 2 + g * 16) ^ ((r & 7) << 4)) >> 1;
#pragma unroll
      for (int m = 0; m < 8; ++m)
        af[m] = *(const f16x8*)&sa[(wm * 128 + m * 16 + r) * 64 + xo];
#pragma unroll
      for (int n = 0; n < 4; ++n)
        bf[n] = *(const f16x8*)&sb[(wn * 64 + n * 16 + r) * 64 + xo];
#pragma unroll
      for (int m = 0; m < 8; ++m)
#pragma unroll
        for (int n = 0; n < 4; ++n)
          acc[m][n] = __builtin_amdgcn_mfma_f32_16x16x32_f16(af[m], bf[n],
                                                             acc[m][n], 0, 0, 0);
    }
    __builtin_amdgcn_s_barrier();
    __builtin_amdgcn_sched_barrier(0);
    if (t + 2 < nt) stage(rb, (t + 2) * 64);
    rb ^= 1;
  }

  // epilogue: exp2 + store f16 + rowsum atomics
  float rs[8][4];
#pragma unroll
  for (int m = 0; m < 8; ++m)
#pragma unroll
    for (int j = 0; j < 4; ++j) rs[m][j] = 0.f;
#pragma unroll
  for (int m = 0; m < 8; ++m)
#pragma unroll
    for (int n = 0; n < 4; ++n)
#pragma unroll
      for (int j = 0; j < 4; ++j) {
        int row = bm * 256 + wm * 128 + m * 16 + g * 4 + j;
        int col = bn * 256 + wn * 64 + n * 16 + r;
        float e = exp2f(acc[m][n][j] * scale - shift);
        C[(long)row * SS + col] = (f16)e;
        rs[m][j] += e;
      }
#pragma unroll
  for (int m = 0; m < 8; ++m)
#pragma unroll
    for (int j = 0; j < 4; ++j) {
      float v = rs[m][j];
      v += __shfl_xor(v, 1);
      v += __shfl_xor(v, 2);
      v += __shfl_xor(v, 4);
      v += __shfl_xor(v, 8);
      if (r == 0)
        atomicAdd(&Ls[bm * 256 + wm * 128 + m * 16 + g * 4 + j], v);
    }
}

// ---- PV: out = (P~ @ V) / L[row],  64x128 tile, RING=3 --------------------
__global__ __launch_bounds__(256) void pv(const f16* __restrict__ Pb,
                                          const f16* __restrict__ Vt,
                                          float* __restrict__ out,
                                          const float* __restrict__ Ls) {
  int z = blockIdx.z;
  int xid = blockIdx.x;               // 128 blocks
  xid = (xid & 7) * 16 + (xid >> 3);  // XCD swizzle
  int bm = xid >> 2, bn = xid & 3;
  gemm_body<64, 3, 2, float>(Pb + (long)z * SS * SS, Vt + (long)z * OO * SS,
                             out + (long)z * SS * OO, Ls + (long)z * SS, bm,
                             bn, SS, SS, SS, OO, 1.f);
}

// ---------------------------------------------------------------------------
extern "C" void kernel_launch(void* const* d_in, const int* in_sizes, int n_in,
                              void* d_out, int out_size, void* d_ws,
                              size_t ws_size, hipStream_t stream) {
  const float* X = (const float*)d_in[0];
  const float* WQ = (const float*)d_in[1];
  const float* WK = (const float*)d_in[2];
  const float* WV = (const float*)d_in[3];
  float* out = (float*)d_out;

  char* ws = (char*)d_ws;
  f16* Xh = (f16*)ws;                    // 8192x1024 f16 = 16 MB
  f16* Wt = (f16*)(ws + 16777216);       // 3 x [512][1024] f16 = 3 MB
  f16* Qh = (f16*)(ws + 19922944);       // 8192x512 f16 = 8 MB (Q then K)
  f16* Vt = (f16*)(ws + 36700160);       // 4 x [512][2048] f16 = 8 MB
  f16* Pb = (f16*)(ws + 45088768);       // 4 x 2048x2048 f16 = 33.5 MB
  float* Ls = (float*)(ws + 78643200);   // 4 x 2048 f32 = 32 KB

  const float kScale = 0.044194173824159216f;  // 1/sqrt(512)
  const float kSclLog2e = kScale * 1.4426950408889634f;
  const float kShift = 12.0f * 1.4426950408889634f;

  // 1) prep: convert X, transpose-convert W, zero Ls
  prep<<<4512, 256, 0, stream>>>(X, Xh, WQ, WK, WV, Wt, Ls);
  // 2) merged Q,K,V projections
  proj_qkv<<<768, 256, 0, stream>>>(Xh, Wt, Qh, Vt);
  // 3) scores+exp (256x256 tiles, 8 waves) + rowsum atomics
  scores256<<<dim3(64, 1, NB), 512, 0, stream>>>(Qh, Qh + (long)8192 * OO, Pb,
                                                 Ls, kSclLog2e, kShift);
  // 4) out = (P~ @ V) / Ls[row]
  pv<<<dim3(128, 1, NB), 256, 0, stream>>>(Pb, Vt, out, Ls);
}

// Round 6
// 100.161 us; speedup vs baseline: 1.6508x; 1.0364x over previous
//
#include <hip/hip_runtime.h>
#include <hip/hip_bf16.h>
#include <hip/hip_fp16.h>

typedef _Float16 f16;
typedef _Float16 f16x8 __attribute__((ext_vector_type(8)));
typedef float f32x4 __attribute__((ext_vector_type(4)));

#define NB 4
#define SS 2048
#define DD 1024
#define OO 512

// ---- prep: cvt X f32->f16 | transpose-cvt W | zero Ls  (flat grid 4512) ---
__global__ __launch_bounds__(256) void prep(const float* __restrict__ X,
                                            f16* __restrict__ Xh,
                                            const float* __restrict__ w0,
                                            const float* __restrict__ w1,
                                            const float* __restrict__ w2,
                                            f16* __restrict__ Wt,
                                            float* __restrict__ Ls) {
  int b = blockIdx.x;
  int tid = threadIdx.x;
  if (b < 4096) {
    int i = b * 256 + tid;
    const float4* xp = (const float4*)X + (size_t)i * 2;
    float4 a = xp[0], c = xp[1];
    f16x8 v;
    v[0] = (f16)a.x; v[1] = (f16)a.y; v[2] = (f16)a.z; v[3] = (f16)a.w;
    v[4] = (f16)c.x; v[5] = (f16)c.y; v[6] = (f16)c.z; v[7] = (f16)c.w;
    *((f16x8*)Xh + i) = v;
  } else if (b < 4480) {
    int rem = b - 4096;                 // 0..383
    int z = rem >> 7;                   // 0..2
    int rem2 = rem & 127;
    int d0 = (rem2 >> 3) * 64;          // 0..15 -> D blocks
    int o0 = (rem2 & 7) * 64;           // 0..7  -> O blocks
    const float* w = z == 0 ? w0 : (z == 1 ? w1 : w2);
    f16* out = Wt + (size_t)z * OO * DD;
    __shared__ float t[64][65];
#pragma unroll
    for (int i = 0; i < 16; ++i) {
      int idx = i * 256 + tid;
      int r = idx >> 6, c = idx & 63;
      t[r][c] = w[(size_t)(d0 + r) * OO + (o0 + c)];
    }
    __syncthreads();
#pragma unroll
    for (int i = 0; i < 16; ++i) {
      int idx = i * 256 + tid;
      int r = idx >> 6, c = idx & 63;
      out[(size_t)(o0 + r) * DD + (d0 + c)] = (f16)t[c][r];
    }
  } else {
    Ls[(b - 4480) * 256 + tid] = 0.f;
  }
}

// --------------- async global -> LDS, 16B per lane ------------------------
__device__ __forceinline__ void gload_lds16(const f16* g, f16* l) {
  __builtin_amdgcn_global_load_lds(
      (const __attribute__((address_space(1))) void*)g,
      (__attribute__((address_space(3))) void*)l, 16, 0, 0);
}

// counted vmcnt wait: leave fut*LPI loads outstanding (immediates only)
template <int LPI>
__device__ __forceinline__ void wait_fut(int fut) {
  if constexpr (LPI == 6) {  // TM=64, RING=3
    if (fut >= 2) asm volatile("s_waitcnt vmcnt(12)" ::: "memory");
    else if (fut == 1) asm volatile("s_waitcnt vmcnt(6)" ::: "memory");
    else asm volatile("s_waitcnt vmcnt(0)" ::: "memory");
  } else {  // LPI==8: RING=2
    if (fut >= 1) asm volatile("s_waitcnt vmcnt(8)" ::: "memory");
    else asm volatile("s_waitcnt vmcnt(0)" ::: "memory");
  }
}

// ---- GEMM body, B-transposed: C[m][n] = sum_k A[m][k]*B[n][k] -------------
// TM x 128 tile, BK=64, 256 threads (4 waves). Ring staging (counted vmcnt,
// raw barriers) + XOR-swizzled LDS.
// MODE 0: C = (OUT_T)(acc*scale);  MODE 2: C = acc / L[row] (float out)
template <int TM, int RING, int MODE, typename OUT_T>
__device__ __forceinline__ void gemm_body(const f16* __restrict__ A,
                                          const f16* __restrict__ B,
                                          OUT_T* __restrict__ C,
                                          const float* __restrict__ L, int bm,
                                          int bn, int K, int lda, int ldb,
                                          int ldc, float scale) {
  constexpr int MF = TM / 32;
  constexpr int LPI = TM / 32 + 4;
  constexpr int SLOT = (TM + 128) * 64;
  __shared__ f16 ring[RING * SLOT];

  int tid = threadIdx.x;
  int lane = tid & 63, wid = tid >> 6;
  int wr = (wid >> 1) * (MF * 16), wc = (wid & 1) << 6;
  int r = lane & 15, g = lane >> 4;

  const f16* Ag = A + (long)(bm * TM) * lda;
  const f16* Bg = B + (long)(bn * 128) * ldb;

  int srow = wid * 8 + (lane >> 3);
  int scol = (((lane & 7) ^ ((lane >> 3) & 7)) << 3);

  f32x4 acc[MF][4] = {};
  int nt = K >> 6;

  auto stage = [&](int si, int k0) {
    f16* s = ring + si * SLOT;
#pragma unroll
    for (int i = 0; i < TM / 32; ++i)
      gload_lds16(Ag + (long)(i * 32 + srow) * lda + k0 + scol,
                  s + i * 2048 + wid * 512);
#pragma unroll
    for (int i = 0; i < 4; ++i)
      gload_lds16(Bg + (long)(i * 32 + srow) * ldb + k0 + scol,
                  s + TM * 64 + i * 2048 + wid * 512);
  };

  for (int p = 0; p < RING && p < nt; ++p) stage(p, p * 64);

  int rb = 0;
  for (int t = 0; t < nt; ++t) {
    int fut = nt - 1 - t;
    if (fut > RING - 1) fut = RING - 1;
    wait_fut<LPI>(fut);
    __builtin_amdgcn_s_barrier();
    __builtin_amdgcn_sched_barrier(0);
    const f16* sa = ring + rb * SLOT;
    const f16* sb = sa + TM * 64;
#pragma unroll
    for (int kk = 0; kk < 64; kk += 32) {
      f16x8 af[MF], bf[4];
      int xo = ((kk * 2 + g * 16) ^ ((r & 7) << 4)) >> 1;
#pragma unroll
      for (int m = 0; m < MF; ++m)
        af[m] = *(const f16x8*)&sa[(wr + m * 16 + r) * 64 + xo];
#pragma unroll
      for (int n = 0; n < 4; ++n)
        bf[n] = *(const f16x8*)&sb[(wc + n * 16 + r) * 64 + xo];
#pragma unroll
      for (int m = 0; m < MF; ++m)
#pragma unroll
        for (int n = 0; n < 4; ++n)
          acc[m][n] = __builtin_amdgcn_mfma_f32_16x16x32_f16(af[m], bf[n],
                                                             acc[m][n], 0, 0, 0);
    }
    __builtin_amdgcn_s_barrier();
    __builtin_amdgcn_sched_barrier(0);
    if (t + RING < nt) stage(rb, (t + RING) * 64);
    rb = (rb + 1 == RING) ? 0 : rb + 1;
  }

  if (MODE == 2) {
    float li[MF][4];
#pragma unroll
    for (int m = 0; m < MF; ++m)
#pragma unroll
      for (int j = 0; j < 4; ++j)
        li[m][j] = 1.0f / L[bm * TM + wr + m * 16 + g * 4 + j];
#pragma unroll
    for (int m = 0; m < MF; ++m)
#pragma unroll
      for (int n = 0; n < 4; ++n)
#pragma unroll
        for (int j = 0; j < 4; ++j) {
          int row = bm * TM + wr + m * 16 + g * 4 + j;
          int col = bn * 128 + wc + n * 16 + r;
          C[(long)row * ldc + col] = (OUT_T)(acc[m][n][j] * li[m][j]);
        }
  } else {
#pragma unroll
    for (int m = 0; m < MF; ++m)
#pragma unroll
      for (int n = 0; n < 4; ++n)
#pragma unroll
        for (int j = 0; j < 4; ++j) {
          int row = bm * TM + wr + m * 16 + g * 4 + j;
          int col = bn * 128 + wc + n * 16 + r;
          C[(long)row * ldc + col] = (OUT_T)(acc[m][n][j] * scale);
        }
  }
}

// ---- merged QK+V projections: flat grid 768 -------------------------------
// id<512: QK proj: Xh[8192,1024] @ Wt(QK stacked,1024 rows)^T -> QKh[8192,1024]
// id>=512: V proj (per batch z): WtV[512,1024] @ Xh_z^T -> Vt[z][512][2048]
__global__ __launch_bounds__(256) void proj_qkv(const f16* __restrict__ Xh,
                                                const f16* __restrict__ Wt,
                                                f16* __restrict__ QKh,
                                                f16* __restrict__ Vt) {
  int id = blockIdx.x;
  if (id < 512) {
    int x = id & 7, j = id >> 3;     // XCD x gets bm in [8x,8x+8), all bn
    int bm = x * 8 + (j >> 3);       // [0,64)
    int bn = j & 7;                  // [0,8)
    gemm_body<128, 2, 0, f16>(Xh, Wt, QKh, nullptr, bm, bn, DD, DD, DD, 1024,
                              1.f);
  } else {
    int vid = id - 512;              // [0,256)
    int x = vid & 7, j = vid >> 3;   // j in [0,32)
    int z = x >> 1;                  // 2 XCDs per batch
    int bn = (x & 1) * 8 + (j >> 2); // [0,16)
    int bm = j & 3;                  // [0,4)
    gemm_body<128, 2, 0, f16>(Wt + 2L * OO * DD, Xh + (long)z * SS * DD,
                              Vt + (long)z * OO * SS, nullptr, bm, bn, DD, DD,
                              DD, SS, 1.f);
  }
}

// ---- scores256: 256x256 tile, 8 waves, 8-phase schedule (T2+T3+T4+T5) -----
// P~ = exp2(Q K^T * scale - shift) -> f16, rowsum atomics into Ls.
// Q = QKh[:, 0:512], K = QKh[:, 512:1024] (lda = ldb = 1024).
__global__ __launch_bounds__(512) void scores256(const f16* __restrict__ QKh,
                                                 f16* __restrict__ P,
                                                 float* __restrict__ L,
                                                 float scale, float shift) {
  int b = blockIdx.x;                // [0,256) flat, XCD = b%8
  int x = b & 7, j = b >> 3;         // j in [0,32)
  int z = x >> 1;                    // 2 XCDs per batch
  int bm = (x & 1) * 4 + (j >> 3);   // [0,8)
  int bn = j & 7;                    // [0,8)

  const f16* A = QKh + (long)z * SS * 1024;        // Q
  const f16* B = QKh + (long)z * SS * 1024 + 512;  // K
  f16* C = P + (long)z * SS * SS;
  float* Ls = L + (long)z * SS;

  __shared__ f16 ring[2 * 32768];  // 128 KB
  int tid = threadIdx.x;
  int lane = tid & 63, wid = tid >> 6;
  int wm = wid >> 2, wn = wid & 3;  // 2M x 4N waves
  int r = lane & 15, g = lane >> 4;

  const f16* Ag = A + (long)(bm * 256) * 1024;
  const f16* Bg = B + (long)(bn * 256) * 1024;

  int srow = tid >> 3;  // 0..63
  int scol = (((tid & 7) ^ ((tid >> 3) & 7)) << 3);

  f32x4 acc[8][4] = {};
  const int nt = 8;  // K=512 / BK=64

  auto stage = [&](int si, int k0) {
    f16* s = ring + si * 32768;
#pragma unroll
    for (int i = 0; i < 4; ++i)
      gload_lds16(Ag + (long)(i * 64 + srow) * 1024 + k0 + scol,
                  s + i * 4096 + tid * 8);
#pragma unroll
    for (int i = 0; i < 4; ++i)
      gload_lds16(Bg + (long)(i * 64 + srow) * 1024 + k0 + scol,
                  s + 16384 + i * 4096 + tid * 8);
  };
  stage(0, 0);
  stage(1, 64);

  int rb = 0;
  int arow = wm * 128 + r, brow = wn * 64 + r;
  for (int t = 0; t < nt; ++t) {
    if (t < nt - 1) asm volatile("s_waitcnt vmcnt(8)" ::: "memory");
    else            asm volatile("s_waitcnt vmcnt(0)" ::: "memory");
    __builtin_amdgcn_s_barrier();
    const f16* sa = ring + rb * 32768;
    const f16* sb = sa + 16384;
    int xo0 = ((g * 16) ^ ((r & 7) << 4)) >> 1;
    int xo1 = ((64 + g * 16) ^ ((r & 7) << 4)) >> 1;
    f16x8 af[4], bf[4];
    // ---- phase 0: m0-3, kk=0 ----
#pragma unroll
    for (int m = 0; m < 4; ++m)
      af[m] = *(const f16x8*)&sa[(arow + m * 16) * 64 + xo0];
#pragma unroll
    for (int n = 0; n < 4; ++n)
      bf[n] = *(const f16x8*)&sb[(brow + n * 16) * 64 + xo0];
    __builtin_amdgcn_s_barrier();
    asm volatile("s_waitcnt lgkmcnt(0)" ::: "memory");
    __builtin_amdgcn_sched_barrier(0);
    __builtin_amdgcn_s_setprio(1);
#pragma unroll
    for (int m = 0; m < 4; ++m)
#pragma unroll
      for (int n = 0; n < 4; ++n)
        acc[m][n] = __builtin_amdgcn_mfma_f32_16x16x32_f16(af[m], bf[n],
                                                           acc[m][n], 0, 0, 0);
    __builtin_amdgcn_s_setprio(0);
    __builtin_amdgcn_s_barrier();
    // ---- phase 1: m4-7, kk=0 ----
#pragma unroll
    for (int m = 0; m < 4; ++m)
      af[m] = *(const f16x8*)&sa[(arow + (m + 4) * 16) * 64 + xo0];
    __builtin_amdgcn_s_barrier();
    asm volatile("s_waitcnt lgkmcnt(0)" ::: "memory");
    __builtin_amdgcn_sched_barrier(0);
    __builtin_amdgcn_s_setprio(1);
#pragma unroll
    for (int m = 0; m < 4; ++m)
#pragma unroll
      for (int n = 0; n < 4; ++n)
        acc[m + 4][n] = __builtin_amdgcn_mfma_f32_16x16x32_f16(
            af[m], bf[n], acc[m + 4][n], 0, 0, 0);
    __builtin_amdgcn_s_setprio(0);
    __builtin_amdgcn_s_barrier();
    // ---- phase 2: m0-3, kk=32 ----
#pragma unroll
    for (int m = 0; m < 4; ++m)
      af[m] = *(const f16x8*)&sa[(arow + m * 16) * 64 + xo1];
#pragma unroll
    for (int n = 0; n < 4; ++n)
      bf[n] = *(const f16x8*)&sb[(brow + n * 16) * 64 + xo1];
    __builtin_amdgcn_s_barrier();
    asm volatile("s_waitcnt lgkmcnt(0)" ::: "memory");
    __builtin_amdgcn_sched_barrier(0);
    __builtin_amdgcn_s_setprio(1);
#pragma unroll
    for (int m = 0; m < 4; ++m)
#pragma unroll
      for (int n = 0; n < 4; ++n)
        acc[m][n] = __builtin_amdgcn_mfma_f32_16x16x32_f16(af[m], bf[n],
                                                           acc[m][n], 0, 0, 0);
    __builtin_amdgcn_s_setprio(0);
    __builtin_amdgcn_s_barrier();
    // ---- phase 3: m4-7, kk=32; stage t+2 after read-complete barrier ----
#pragma unroll
    for (int m = 0; m < 4; ++m)
      af[m] = *(const f16x8*)&sa[(arow + (m + 4) * 16) * 64 + xo1];
    asm volatile("s_waitcnt lgkmcnt(0)" ::: "memory");
    __builtin_amdgcn_sched_barrier(0);
    __builtin_amdgcn_s_barrier();   // all waves done reading slot rb
    if (t + 2 < nt) stage(rb, (t + 2) * 64);
    __builtin_amdgcn_s_setprio(1);
#pragma unroll
    for (int m = 0; m < 4; ++m)
#pragma unroll
      for (int n = 0; n < 4; ++n)
        acc[m + 4][n] = __builtin_amdgcn_mfma_f32_16x16x32_f16(
            af[m], bf[n], acc[m + 4][n], 0, 0, 0);
    __builtin_amdgcn_s_setprio(0);
    __builtin_amdgcn_s_barrier();
    rb ^= 1;
  }

  // epilogue: exp2 + store f16 + rowsum atomics
  float rs[8][4];
#pragma unroll
  for (int m = 0; m < 8; ++m)
#pragma unroll
    for (int jj = 0; jj < 4; ++jj) rs[m][jj] = 0.f;
#pragma unroll
  for (int m = 0; m < 8; ++m)
#pragma unroll
    for (int n = 0; n < 4; ++n)
#pragma unroll
      for (int jj = 0; jj < 4; ++jj) {
        int row = bm * 256 + wm * 128 + m * 16 + g * 4 + jj;
        int col = bn * 256 + wn * 64 + n * 16 + r;
        float e = exp2f(acc[m][n][jj] * scale - shift);
        C[(long)row * SS + col] = (f16)e;
        rs[m][jj] += e;
      }
#pragma unroll
  for (int m = 0; m < 8; ++m)
#pragma unroll
    for (int jj = 0; jj < 4; ++jj) {
      float v = rs[m][jj];
      v += __shfl_xor(v, 1);
      v += __shfl_xor(v, 2);
      v += __shfl_xor(v, 4);
      v += __shfl_xor(v, 8);
      if (r == 0)
        atomicAdd(&Ls[bm * 256 + wm * 128 + m * 16 + g * 4 + jj], v);
    }
}

// ---- PV: out = (P~ @ V) / L[row],  64x128 tile, RING=3 --------------------
__global__ __launch_bounds__(256) void pv(const f16* __restrict__ Pb,
                                          const f16* __restrict__ Vt,
                                          float* __restrict__ out,
                                          const float* __restrict__ Ls) {
  int b = blockIdx.x;               // [0,512) flat, XCD = b%8
  int x = b & 7, k = b >> 3;        // k in [0,64)
  int z = x >> 1;                   // 2 XCDs per batch
  int bm = (x & 1) * 16 + (k >> 2); // [0,32); 4 bn-blocks of same bm adjacent
  int bn = k & 3;                   // [0,4)
  gemm_body<64, 3, 2, float>(Pb + (long)z * SS * SS, Vt + (long)z * OO * SS,
                             out + (long)z * SS * OO, Ls + (long)z * SS, bm,
                             bn, SS, SS, SS, OO, 1.f);
}

// ---------------------------------------------------------------------------
extern "C" void kernel_launch(void* const* d_in, const int* in_sizes, int n_in,
                              void* d_out, int out_size, void* d_ws,
                              size_t ws_size, hipStream_t stream) {
  const float* X = (const float*)d_in[0];
  const float* WQ = (const float*)d_in[1];
  const float* WK = (const float*)d_in[2];
  const float* WV = (const float*)d_in[3];
  float* out = (float*)d_out;

  char* ws = (char*)d_ws;
  f16* Xh = (f16*)ws;                    // 8192x1024 f16 = 16 MB
  f16* Wt = (f16*)(ws + 16777216);       // 3 x [512][1024] f16 = 3 MB (Q,K,V)
  f16* QKh = (f16*)(ws + 19922944);      // 8192x1024 f16 = 16 MB (Q|K cols)
  f16* Vt = (f16*)(ws + 36700160);       // 4 x [512][2048] f16 = 8 MB
  f16* Pb = (f16*)(ws + 45088768);       // 4 x 2048x2048 f16 = 33.5 MB
  float* Ls = (float*)(ws + 78643200);   // 4 x 2048 f32 = 32 KB

  const float kScale = 0.044194173824159216f;  // 1/sqrt(512)
  const float kSclLog2e = kScale * 1.4426950408889634f;
  const float kShift = 12.0f * 1.4426950408889634f;

  // 1) prep: convert X, transpose-convert W, zero Ls
  prep<<<4512, 256, 0, stream>>>(X, Xh, WQ, WK, WV, Wt, Ls);
  // 2) merged QK (one N=1024 GEMM) + V^T projections
  proj_qkv<<<768, 256, 0, stream>>>(Xh, Wt, QKh, Vt);
  // 3) scores+exp (256x256, 8 waves, 8-phase) + rowsum atomics
  scores256<<<256, 512, 0, stream>>>(QKh, Pb, Ls, kSclLog2e, kShift);
  // 4) out = (P~ @ V) / Ls[row]
  pv<<<512, 256, 0, stream>>>(Pb, Vt, out, Ls);
}